// Round 9
// baseline (267.107 us; speedup 1.0000x reference)
//
#include <hip/hip_runtime.h>

// Single causal attention head: B=16, T=2048, C=1024, H=64.
// pack_w: W fp32 -> bf16 Wp, layout matched to global_load_lds B-staging.
// proj:   x[32768,1024]fp32 x Wp -> Q(pre-scaled by 0.125*log2e),K row-major
//         bf16 + Vt[b][h][t] bf16. BARRIER-FREE COUNTED-VMCNT PIPELINE:
//         block = 128 thr = 2 waves; wave w owns cols w*96..+95 (cts w*6..+5)
//         over all 32 rows and stages its own B-slice into wave-PRIVATE LDS
//         (no cross-wave deps -> zero __syncthreads). Per phase: issue 20
//         vmem ops (12 global_load_lds + 8 x-loads), s_waitcnt vmcnt(20)
//         (drains previous phase only, keeps this phase in flight), then
//         compute. T4 mechanism; rule-18 sched_barrier(0) fence after wait.
// flash:  64 q-rows/block, 4 waves stride kv-tiles (split-kv), wave computes
//         all 4 q-subtiles per tile. XCD-aware mapping: batches {b, b+8} on
//         XCD b -> per-XCD L2 working set 1.5 MB < 4 MB. K frags held in
//         regs across both q-halves. Swapped QK^T -> lane-local online
//         softmax, exact defer-max, cvt_pk + swizzled P LDS, swapped PV.
//
// MFMA 16x16x32 bf16 layouts (HW-verified):
//   A[m][k]: m = lane&15, k = (lane>>4)*8 + j
//   B[k][n]: n = lane&15, k = (lane>>4)*8 + j
//   C/D:     col(n) = lane&15, row(m) = (lane>>4)*4 + reg

typedef float  floatx4 __attribute__((ext_vector_type(4)));
typedef __bf16 bf16x8  __attribute__((ext_vector_type(8)));
typedef unsigned short ushort4v __attribute__((ext_vector_type(4)));
typedef unsigned int   uint2v   __attribute__((ext_vector_type(2)));
typedef unsigned int   uint4v   __attribute__((ext_vector_type(4)));

constexpr int Bn = 16;
constexpr int Tn = 2048;
constexpr int Cn = 1024;
constexpr int Hn = 64;
constexpr int BT = Bn * Tn;

// H^-0.5 * log2(e): scores come out in log2 units -> v_exp_f32 directly.
constexpr float QSCALE = 0.125f * 1.44269504088896340736f;

__device__ __forceinline__ unsigned short f2b(float f) {
  unsigned int u = __builtin_bit_cast(unsigned int, f);
  u += 0x7fffu + ((u >> 16) & 1u);
  return (unsigned short)(u >> 16);
}

__device__ __forceinline__ unsigned int cvt_pk_bf16(float lo, float hi) {
  unsigned int r;
  asm("v_cvt_pk_bf16_f32 %0, %1, %2" : "=v"(r) : "v"(lo), "v"(hi));
  return r;
}

// ---------------------------------------------------------------------------
// Wp[ct 0..11][kb 0..127][c 0..15][j 0..7] bf16  (global col = ct*16+c, k = kb*8+j)
// ---------------------------------------------------------------------------
__global__ __launch_bounds__(256) void pack_w(const float* __restrict__ Wq,
                                              const float* __restrict__ Wk,
                                              const float* __restrict__ Wv,
                                              unsigned short* __restrict__ Wp) {
  int gid = blockIdx.x * 256 + threadIdx.x;
  int mat = gid >> 16;
  int rem = gid & 65535;
  int k   = rem >> 6;
  int col = rem & 63;
  const float* W = (mat == 0) ? Wq : (mat == 1) ? Wk : Wv;
  float v = W[rem];
  int kb = k >> 3, j = k & 7, ct = (mat << 2) | (col >> 4), c = col & 15;
  size_t idx = ((((size_t)ct * 128) + kb) * 16 + c) * 8 + j;
  Wp[idx] = f2b(v);
}

// ---------------------------------------------------------------------------
// proj: block = 128 thr = 2 waves, tile 32 rows x 192 cols, BK=64, grid 1024.
// Wave w: all 32 rows x cols w*96..+95 (cts w*6..+5), wave-private LDS
// B-slice (Bl[wave][buf], 12 KB each). Zero barriers; counted vmcnt(20)
// keeps one full phase of loads in flight across each compute phase.
// ---------------------------------------------------------------------------
__global__ __launch_bounds__(128, 2) void proj_kernel(
    const float* __restrict__ x, const unsigned short* __restrict__ Wp,
    unsigned short* __restrict__ Q, unsigned short* __restrict__ K,
    unsigned short* __restrict__ Vt) {
  __shared__ alignas(16) unsigned short Bl[2][2][6 * 1024];  // [wave][buf]

  const int tid  = threadIdx.x;
  const int wave = tid >> 6;     // 0..1 = column half
  const int lane = tid & 63;
  const int quad = lane >> 4;
  const int l16  = lane & 15;
  const int rbase = blockIdx.x * 32;

  floatx4 acc[2][6];
#pragma unroll
  for (int a = 0; a < 2; ++a)
#pragma unroll
    for (int b = 0; b < 6; ++b) acc[a][b] = (floatx4){0.f, 0.f, 0.f, 0.f};

  // per-lane A pointer: row = rbase + rg*16 + l16, col base = quad*8
  const float* xp = x + (size_t)(rbase + l16) * Cn + quad * 8;

  // stage this wave's 6 cts for K-step t into private buf: 12 global_load_lds
  auto stageB = [&](int t, int buf) {
    const int kb0 = t << 3;
#pragma unroll
    for (int c6 = 0; c6 < 6; ++c6) {
      const int ct = wave * 6 + c6;
#pragma unroll
      for (int h = 0; h < 2; ++h) {
        const unsigned short* g =
            Wp + ((size_t)(ct * 128 + kb0 + h * 4 + quad) * 16 + l16) * 8;
        __builtin_amdgcn_global_load_lds(
            (const __attribute__((address_space(1))) void*)g,
            (__attribute__((address_space(3))) void*)
                &Bl[wave][buf][c6 * 1024 + h * 512],
            16, 0, 0);
      }
    }
  };

  // 8 global_load_dwordx4 per lane (both row-groups)
  auto loadX = [&](int t, floatx4 (&fa)[2][2][2]) {
    const float* bp = xp + t * 64;
#pragma unroll
    for (int rg = 0; rg < 2; ++rg) {
      const float* rp = bp + rg * 16 * Cn;
      fa[rg][0][0] = *reinterpret_cast<const floatx4*>(rp);
      fa[rg][0][1] = *reinterpret_cast<const floatx4*>(rp + 4);
      fa[rg][1][0] = *reinterpret_cast<const floatx4*>(rp + 32);
      fa[rg][1][1] = *reinterpret_cast<const floatx4*>(rp + 36);
    }
  };

  auto compute = [&](const floatx4 (&fa)[2][2][2], int buf) {
    bf16x8 af[2][2];
#pragma unroll
    for (int rg = 0; rg < 2; ++rg)
#pragma unroll
      for (int kk = 0; kk < 2; ++kk) {
        uint4v u;
        u[0] = cvt_pk_bf16(fa[rg][kk][0][0], fa[rg][kk][0][1]);
        u[1] = cvt_pk_bf16(fa[rg][kk][0][2], fa[rg][kk][0][3]);
        u[2] = cvt_pk_bf16(fa[rg][kk][1][0], fa[rg][kk][1][1]);
        u[3] = cvt_pk_bf16(fa[rg][kk][1][2], fa[rg][kk][1][3]);
        af[rg][kk] = __builtin_bit_cast(bf16x8, u);
      }
    __builtin_amdgcn_s_setprio(1);
#pragma unroll
    for (int kk = 0; kk < 2; ++kk) {
#pragma unroll
      for (int c6 = 0; c6 < 6; ++c6) {
        bf16x8 bfr = *reinterpret_cast<const bf16x8*>(
            &Bl[wave][buf][c6 * 1024 + (kk * 4 + quad) * 128 + l16 * 8]);
        acc[0][c6] = __builtin_amdgcn_mfma_f32_16x16x32_bf16(af[0][kk], bfr, acc[0][c6], 0, 0, 0);
        acc[1][c6] = __builtin_amdgcn_mfma_f32_16x16x32_bf16(af[1][kk], bfr, acc[1][c6], 0, 0, 0);
      }
    }
    __builtin_amdgcn_s_setprio(0);
  };

  floatx4 fa0[2][2][2], fa1[2][2][2];

  // prologue: 20 vmem ops for t=0 in flight
  loadX(0, fa0);
  stageB(0, 0);

  for (int tt = 0; tt < 8; ++tt) {
    const int t = tt * 2;
    // phase A: issue t+1 (20 ops) -> wait for t's 20 -> compute t
    stageB(t + 1, 1);
    loadX(t + 1, fa1);
    asm volatile("s_waitcnt vmcnt(20)" ::: "memory");
    __builtin_amdgcn_sched_barrier(0);
    compute(fa0, 0);
    // phase B: issue t+2 (20 ops) -> wait for t+1's 20 -> compute t+1
    if (t + 2 < 16) {
      stageB(t + 2, 0);
      loadX(t + 2, fa0);
      asm volatile("s_waitcnt vmcnt(20)" ::: "memory");
    } else {
      asm volatile("s_waitcnt vmcnt(0)" ::: "memory");
    }
    __builtin_amdgcn_sched_barrier(0);
    compute(fa1, 1);
  }

#pragma unroll
  for (int c6 = 0; c6 < 6; ++c6) {
    const int cbase = wave * 96 + c6 * 16;
#pragma unroll
    for (int rg = 0; rg < 2; ++rg) {
      const int rowloc = rg * 16 + quad * 4;
      if (cbase < 64) {
#pragma unroll
        for (int r = 0; r < 4; ++r)
          Q[(size_t)(rbase + rowloc + r) * Hn + cbase + l16] =
              f2b(acc[rg][c6][r] * QSCALE);
      } else if (cbase < 128) {
#pragma unroll
        for (int r = 0; r < 4; ++r)
          K[(size_t)(rbase + rowloc + r) * Hn + cbase - 64 + l16] =
              f2b(acc[rg][c6][r]);
      } else {
        const int b  = rbase >> 11;
        const int t0 = (rbase & 2047) + rowloc;
        const int h  = cbase - 128 + l16;
        ushort4v v;
#pragma unroll
        for (int r = 0; r < 4; ++r) v[r] = f2b(acc[rg][c6][r]);
        *reinterpret_cast<ushort4v*>(&Vt[((size_t)b * Hn + h) * Tn + t0]) = v;
      }
    }
  }
}

// ---------------------------------------------------------------------------
// flash: block = 256 thr = 4 waves, 64 q-rows (4 subtiles of 16).
// XCD-aware mapping: XCD = blockIdx%8 (HW round-robin); batch = xcd|((j&1)<<3)
// puts batches {b, b+8} entirely on XCD b -> Q/K/Vt L2-resident (1.5 MB/XCD).
// Wave w handles kv tiles kt = w, w+4, ... for all 4 q-subtiles.
// ---------------------------------------------------------------------------
__global__ __launch_bounds__(256) void flash_kernel(
    const unsigned short* __restrict__ Q, const unsigned short* __restrict__ K,
    const unsigned short* __restrict__ Vt, float* __restrict__ out) {
  __shared__ alignas(16) unsigned short P[4][16][64];  // per-wave, XOR-swizzled
  __shared__ alignas(16) float Om[4][16][68];          // merge: O partials [q][h]
  __shared__ float Ml[4][16][2];                       // merge: m,l per q-row

  const int tid  = threadIdx.x;
  const int wave = tid >> 6;
  const int lane = tid & 63;
  const int quad = lane >> 4;
  const int l16  = lane & 15;

  const int xcd = blockIdx.x & 7;
  const int jb  = blockIdx.x >> 3;           // 0..63
  const int b   = xcd | ((jb & 1) << 3);     // batches {xcd, xcd+8} on XCD xcd
  const int p   = 31 - (jb >> 1);            // heavy q-blocks first
  const int qbase = p * 64;
  const int n_tiles  = p + 1;                // kv tiles of 64 needed
  const int lastTile = p;
  const size_t bbase  = (size_t)b * Tn * Hn;
  const size_t vtbase = (size_t)b * Hn * Tn;

  // B-operand (Q): B[k=h][n=qrow]: lane reads Q[qbase+qt*16+l16][kk*32+quad*8+j]
  bf16x8 qf[4][2];
#pragma unroll
  for (int qt = 0; qt < 4; ++qt)
#pragma unroll
    for (int i = 0; i < 2; ++i)
      qf[qt][i] = *reinterpret_cast<const bf16x8*>(
          &Q[bbase + (size_t)(qbase + qt * 16 + l16) * Hn + i * 32 + quad * 8]);

  // O^T[qt][h = ht*16 + quad*4 + r][q = l16]
  floatx4 O[4][4];
#pragma unroll
  for (int qt = 0; qt < 4; ++qt)
#pragma unroll
    for (int i = 0; i < 4; ++i) O[qt][i] = (floatx4){0.f, 0.f, 0.f, 0.f};
  float m_r[4], l_r[4];
#pragma unroll
  for (int qt = 0; qt < 4; ++qt) { m_r[qt] = -INFINITY; l_r[qt] = 0.f; }

  const int swz = (l16 & 7) << 3;   // 16B-block XOR swizzle (short units)

  for (int kt = wave; kt < n_tiles; kt += 4) {
    const int kvbase = kt * 64;

    // K fragments once per tile, held across both q-halves (2x reuse);
    // V fragments once per tile (4x reuse). Latency hides under QK^T.
    bf16x8 kf[4][2];
#pragma unroll
    for (int ct = 0; ct < 4; ++ct) {
      const unsigned short* kp =
          &K[bbase + (size_t)(kvbase + ct * 16 + l16) * Hn + quad * 8];
      kf[ct][0] = *reinterpret_cast<const bf16x8*>(kp);
      kf[ct][1] = *reinterpret_cast<const bf16x8*>(kp + 32);
    }
    bf16x8 vf[4][2];
#pragma unroll
    for (int ht = 0; ht < 4; ++ht)
#pragma unroll
      for (int kk = 0; kk < 2; ++kk)
        vf[ht][kk] = *reinterpret_cast<const bf16x8*>(
            &Vt[vtbase + (size_t)(ht * 16 + l16) * Tn + kvbase + kk * 32 + quad * 8]);

#pragma unroll
    for (int half = 0; half < 2; ++half) {
      // S^T = mfma(A=K, B=Q) for q-subtiles {2*half, 2*half+1}
      floatx4 S[2][4];
      __builtin_amdgcn_s_setprio(1);
#pragma unroll
      for (int ct = 0; ct < 4; ++ct) {
#pragma unroll
        for (int q2 = 0; q2 < 2; ++q2) {
          const int qt = half * 2 + q2;
          floatx4 s = (floatx4){0.f, 0.f, 0.f, 0.f};
          s = __builtin_amdgcn_mfma_f32_16x16x32_bf16(kf[ct][0], qf[qt][0], s, 0, 0, 0);
          s = __builtin_amdgcn_mfma_f32_16x16x32_bf16(kf[ct][1], qf[qt][1], s, 0, 0, 0);
          S[q2][ct] = s;
        }
      }
      __builtin_amdgcn_s_setprio(0);

#pragma unroll
      for (int q2 = 0; q2 < 2; ++q2) {
        const int qt = half * 2 + q2;
        const int trow = qbase + qt * 16 + l16;

        // causal mask — only the globally-last tile crosses the diagonal
        if (kt == lastTile) {
#pragma unroll
          for (int ct = 0; ct < 4; ++ct)
#pragma unroll
            for (int r = 0; r < 4; ++r)
              if (kvbase + ct * 16 + quad * 4 + r > trow) S[q2][ct][r] = -1e30f;
        }

        // online softmax: lane owns q-row; local tree + 2 cross-quad
        // shfl_xor. Exact defer-max: rescale only when the max grows.
        float mx0 = fmaxf(fmaxf(S[q2][0][0], S[q2][0][1]), fmaxf(S[q2][0][2], S[q2][0][3]));
        float mx1 = fmaxf(fmaxf(S[q2][1][0], S[q2][1][1]), fmaxf(S[q2][1][2], S[q2][1][3]));
        float mx2 = fmaxf(fmaxf(S[q2][2][0], S[q2][2][1]), fmaxf(S[q2][2][2], S[q2][2][3]));
        float mx3 = fmaxf(fmaxf(S[q2][3][0], S[q2][3][1]), fmaxf(S[q2][3][2], S[q2][3][3]));
        float mx  = fmaxf(fmaxf(mx0, mx1), fmaxf(mx2, mx3));
        mx = fmaxf(mx, __shfl_xor(mx, 16));
        mx = fmaxf(mx, __shfl_xor(mx, 32));
        if (mx > m_r[qt]) {
          float alpha = __builtin_amdgcn_exp2f(m_r[qt] - mx);
          l_r[qt] *= alpha;
#pragma unroll
          for (int ht = 0; ht < 4; ++ht)
#pragma unroll
            for (int r = 0; r < 4; ++r) O[qt][ht][r] *= alpha;
          m_r[qt] = mx;
        }
        float rs = 0.f;
#pragma unroll
        for (int ct = 0; ct < 4; ++ct)
#pragma unroll
          for (int r = 0; r < 4; ++r) {
            float pv = __builtin_amdgcn_exp2f(S[q2][ct][r] - m_r[qt]);
            S[q2][ct][r] = pv;
            rs += pv;
          }
        rs += __shfl_xor(rs, 16);
        rs += __shfl_xor(rs, 32);
        l_r[qt] += rs;

        // pack P -> bf16 pairs, swizzled ds_write_b64, read B-frags b128.
        // Same-wave DS ordering: no barrier.
#pragma unroll
        for (int ct = 0; ct < 4; ++ct) {
          uint2v w;
          w[0] = cvt_pk_bf16(S[q2][ct][0], S[q2][ct][1]);
          w[1] = cvt_pk_bf16(S[q2][ct][2], S[q2][ct][3]);
          *reinterpret_cast<uint2v*>(&P[wave][l16][(ct * 16 + quad * 4) ^ swz]) = w;
        }
        bf16x8 pf0 = *reinterpret_cast<const bf16x8*>(&P[wave][l16][(quad * 8) ^ swz]);
        bf16x8 pf1 = *reinterpret_cast<const bf16x8*>(&P[wave][l16][(32 + quad * 8) ^ swz]);

        __builtin_amdgcn_s_setprio(1);
#pragma unroll
        for (int ht = 0; ht < 4; ++ht) {
          O[qt][ht] = __builtin_amdgcn_mfma_f32_16x16x32_bf16(vf[ht][0], pf0, O[qt][ht], 0, 0, 0);
          O[qt][ht] = __builtin_amdgcn_mfma_f32_16x16x32_bf16(vf[ht][1], pf1, O[qt][ht], 0, 0, 0);
        }
        __builtin_amdgcn_s_setprio(0);
      }
    }
  }

  // ---- per-subtile 4-way merge across waves ----
#pragma unroll
  for (int qt = 0; qt < 4; ++qt) {
#pragma unroll
    for (int ht = 0; ht < 4; ++ht)
#pragma unroll
      for (int r = 0; r < 4; ++r)
        Om[wave][l16][ht * 16 + quad * 4 + r] = O[qt][ht][r];
    if (quad == 0) {
      Ml[wave][l16][0] = m_r[qt];
      Ml[wave][l16][1] = l_r[qt];
    }
    __syncthreads();

    {
      const int row = tid >> 4;           // 0..15
      const int c4  = (tid & 15) * 4;     // 0,4,..,60
      float m0 = Ml[0][row][0], m1 = Ml[1][row][0];
      float m2 = Ml[2][row][0], m3 = Ml[3][row][0];
      float M = fmaxf(fmaxf(m0, m1), fmaxf(m2, m3));
      float e0 = __builtin_amdgcn_exp2f(m0 - M), e1 = __builtin_amdgcn_exp2f(m1 - M);
      float e2 = __builtin_amdgcn_exp2f(m2 - M), e3 = __builtin_amdgcn_exp2f(m3 - M);
      float L = Ml[0][row][1] * e0 + Ml[1][row][1] * e1 +
                Ml[2][row][1] * e2 + Ml[3][row][1] * e3;
      float invL = 1.0f / L;
      floatx4 o0 = *reinterpret_cast<const floatx4*>(&Om[0][row][c4]);
      floatx4 o1 = *reinterpret_cast<const floatx4*>(&Om[1][row][c4]);
      floatx4 o2 = *reinterpret_cast<const floatx4*>(&Om[2][row][c4]);
      floatx4 o3 = *reinterpret_cast<const floatx4*>(&Om[3][row][c4]);
      floatx4 res;
#pragma unroll
      for (int jj = 0; jj < 4; ++jj)
        res[jj] = (o0[jj] * e0 + o1[jj] * e1 + o2[jj] * e2 + o3[jj] * e3) * invL;
      *reinterpret_cast<floatx4*>(
          &out[bbase + (size_t)(qbase + qt * 16 + row) * Hn + c4]) = res;
    }
    __syncthreads();
  }
}

// ---------------------------------------------------------------------------
extern "C" void kernel_launch(void* const* d_in, const int* in_sizes, int n_in,
                              void* d_out, int out_size, void* d_ws, size_t ws_size,
                              hipStream_t stream) {
  const float* x  = (const float*)d_in[0];
  const float* Wq = (const float*)d_in[1];
  const float* Wk = (const float*)d_in[2];
  const float* Wv = (const float*)d_in[3];
  float* out = (float*)d_out;

  char* ws = (char*)d_ws;
  unsigned short* Q  = (unsigned short*)(ws);
  unsigned short* Kb = (unsigned short*)(ws + ((size_t)4 << 20));
  unsigned short* Vt = (unsigned short*)(ws + ((size_t)8 << 20));
  unsigned short* Wp = (unsigned short*)(ws + ((size_t)12 << 20));

  pack_w<<<dim3(768), dim3(256), 0, stream>>>(Wq, Wk, Wv, Wp);
  proj_kernel<<<dim3(BT / 32), dim3(128), 0, stream>>>(x, Wp, Q, Kb, Vt);
  flash_kernel<<<dim3(16 * 32), dim3(256), 0, stream>>>(Q, Kb, Vt, out);
}

// Round 10
// 245.460 us; speedup vs baseline: 1.0882x; 1.0882x over previous
//
#include <hip/hip_runtime.h>

// Single causal attention head: B=16, T=2048, C=1024, H=64.
// pack_w: W fp32 -> bf16 Wp, layout matched to global_load_lds B-staging.
// proj:   x[32768,1024]fp32 x Wp -> Q(pre-scaled by 0.125*log2e),K row-major
//         bf16 + Vt[b][h][t] bf16. 2-phase LDS pipeline (R7-verified
//         structure) widened to 8 WAVES / 512 THREADS per 64-row tile:
//         wave = (wr row-16, wc col-96), 12 MFMA/wave/step, staging split
//         3 global_load_lds/wave. Grid 512 -> 2 blocks/CU = 4 waves/SIMD
//         (2x R7's TLP; proj is latency-bound per R7-R9 counter ranking).
// flash:  64 q-rows/block, 4 waves stride kv-tiles (split-kv), wave computes
//         all 4 q-subtiles per tile. XCD-aware mapping: batches {b, b+8} on
//         XCD b -> per-XCD L2 working set 1.5 MB < 4 MB. K frags held in
//         regs across both q-halves. Swapped QK^T -> lane-local online
//         softmax, exact defer-max, cvt_pk + swizzled P LDS, swapped PV.
//
// MFMA 16x16x32 bf16 layouts (HW-verified):
//   A[m][k]: m = lane&15, k = (lane>>4)*8 + j
//   B[k][n]: n = lane&15, k = (lane>>4)*8 + j
//   C/D:     col(n) = lane&15, row(m) = (lane>>4)*4 + reg

typedef float  floatx4 __attribute__((ext_vector_type(4)));
typedef __bf16 bf16x8  __attribute__((ext_vector_type(8)));
typedef unsigned short ushort4v __attribute__((ext_vector_type(4)));
typedef unsigned int   uint2v   __attribute__((ext_vector_type(2)));
typedef unsigned int   uint4v   __attribute__((ext_vector_type(4)));

constexpr int Bn = 16;
constexpr int Tn = 2048;
constexpr int Cn = 1024;
constexpr int Hn = 64;
constexpr int BT = Bn * Tn;

// H^-0.5 * log2(e): scores come out in log2 units -> v_exp_f32 directly.
constexpr float QSCALE = 0.125f * 1.44269504088896340736f;

__device__ __forceinline__ unsigned short f2b(float f) {
  unsigned int u = __builtin_bit_cast(unsigned int, f);
  u += 0x7fffu + ((u >> 16) & 1u);
  return (unsigned short)(u >> 16);
}

__device__ __forceinline__ unsigned int cvt_pk_bf16(float lo, float hi) {
  unsigned int r;
  asm("v_cvt_pk_bf16_f32 %0, %1, %2" : "=v"(r) : "v"(lo), "v"(hi));
  return r;
}

// ---------------------------------------------------------------------------
// Wp[ct 0..11][kb 0..127][c 0..15][j 0..7] bf16  (global col = ct*16+c, k = kb*8+j)
// ---------------------------------------------------------------------------
__global__ __launch_bounds__(256) void pack_w(const float* __restrict__ Wq,
                                              const float* __restrict__ Wk,
                                              const float* __restrict__ Wv,
                                              unsigned short* __restrict__ Wp) {
  int gid = blockIdx.x * 256 + threadIdx.x;
  int mat = gid >> 16;
  int rem = gid & 65535;
  int k   = rem >> 6;
  int col = rem & 63;
  const float* W = (mat == 0) ? Wq : (mat == 1) ? Wk : Wv;
  float v = W[rem];
  int kb = k >> 3, j = k & 7, ct = (mat << 2) | (col >> 4), c = col & 15;
  size_t idx = ((((size_t)ct * 128) + kb) * 16 + c) * 8 + j;
  Wp[idx] = f2b(v);
}

// ---------------------------------------------------------------------------
// proj: block = 512 thr = 8 waves, tile 64 rows x 192 cols, BK=64, grid 512.
// Wave w: rows wr*16..+15 (wr=w>>1), cols wc*96..+95 (wc=w&1). Per K-step:
// {x loads -> fa_nxt, B global_load_lds (3/wave) -> Bl[nxt]}, compute
// {cvt, ds_read, 12 MFMA}, ONE __syncthreads. 48 KB LDS, 2 blocks/CU.
// ---------------------------------------------------------------------------
__global__ __launch_bounds__(512, 4) void proj_kernel(
    const float* __restrict__ x, const unsigned short* __restrict__ Wp,
    unsigned short* __restrict__ Q, unsigned short* __restrict__ K,
    unsigned short* __restrict__ Vt) {
  __shared__ alignas(16) unsigned short Bl[2][12 * 1024];

  const int tid  = threadIdx.x;
  const int wave = tid >> 6;     // 0..7
  const int lane = tid & 63;
  const int quad = lane >> 4;
  const int l16  = lane & 15;
  const int wr   = wave >> 1;    // 0..3 row-sixteenth
  const int wc   = wave & 1;     // 0..1 col-half
  const int rbase = blockIdx.x * 64;

  floatx4 acc[6];
#pragma unroll
  for (int b = 0; b < 6; ++b) acc[b] = (floatx4){0.f, 0.f, 0.f, 0.f};

  // per-lane A pointer: row = rbase + wr*16 + l16, col base = quad*8
  const float* xp = x + (size_t)(rbase + wr * 16 + l16) * Cn + quad * 8;

  // 24 (ct,h) staging slots spread over 8 waves x 3: p = wave*3+i,
  // ct = p>>1, h = p&1  (bijection onto 12 cts x 2 halves).
  auto stageB = [&](int t, int buf) {
    const int kb0 = t << 3;
#pragma unroll
    for (int i = 0; i < 3; ++i) {
      const int p  = wave * 3 + i;
      const int ct = p >> 1;
      const int h  = p & 1;
      const unsigned short* g =
          Wp + ((size_t)(ct * 128 + kb0 + h * 4 + quad) * 16 + l16) * 8;
      __builtin_amdgcn_global_load_lds(
          (const __attribute__((address_space(1))) void*)g,
          (__attribute__((address_space(3))) void*)&Bl[buf][ct * 1024 + h * 512],
          16, 0, 0);
    }
  };

  auto loadX = [&](int t, floatx4 (&fa)[2][2]) {
    const float* bp = xp + t * 64;
    fa[0][0] = *reinterpret_cast<const floatx4*>(bp);
    fa[0][1] = *reinterpret_cast<const floatx4*>(bp + 4);
    fa[1][0] = *reinterpret_cast<const floatx4*>(bp + 32);
    fa[1][1] = *reinterpret_cast<const floatx4*>(bp + 36);
  };

  auto compute = [&](const floatx4 (&fa)[2][2], int buf) {
    bf16x8 af[2];
#pragma unroll
    for (int kk = 0; kk < 2; ++kk) {
      uint4v u;
      u[0] = cvt_pk_bf16(fa[kk][0][0], fa[kk][0][1]);
      u[1] = cvt_pk_bf16(fa[kk][0][2], fa[kk][0][3]);
      u[2] = cvt_pk_bf16(fa[kk][1][0], fa[kk][1][1]);
      u[3] = cvt_pk_bf16(fa[kk][1][2], fa[kk][1][3]);
      af[kk] = __builtin_bit_cast(bf16x8, u);
    }
    __builtin_amdgcn_s_setprio(1);
#pragma unroll
    for (int kk = 0; kk < 2; ++kk) {
#pragma unroll
      for (int c6 = 0; c6 < 6; ++c6) {
        const int ct = wc * 6 + c6;
        bf16x8 bfr = *reinterpret_cast<const bf16x8*>(
            &Bl[buf][ct * 1024 + (kk * 4 + quad) * 128 + l16 * 8]);
        acc[c6] = __builtin_amdgcn_mfma_f32_16x16x32_bf16(af[kk], bfr, acc[c6], 0, 0, 0);
      }
    }
    __builtin_amdgcn_s_setprio(0);
  };

  floatx4 fa0[2][2], fa1[2][2];

  loadX(0, fa0);
  stageB(0, 0);
  __syncthreads();

  for (int tt = 0; tt < 8; ++tt) {
    const int tb = tt * 2 + 1;
    loadX(tb, fa1);
    stageB(tb, 1);
    compute(fa0, 0);
    __syncthreads();
    if (tb + 1 < 16) {
      loadX(tb + 1, fa0);
      stageB(tb + 1, 0);
    }
    compute(fa1, 1);
    __syncthreads();
  }

#pragma unroll
  for (int c6 = 0; c6 < 6; ++c6) {
    const int cbase  = wc * 96 + c6 * 16;
    const int rowloc = wr * 16 + quad * 4;
    if (cbase < 64) {
#pragma unroll
      for (int r = 0; r < 4; ++r)
        Q[(size_t)(rbase + rowloc + r) * Hn + cbase + l16] =
            f2b(acc[c6][r] * QSCALE);
    } else if (cbase < 128) {
#pragma unroll
      for (int r = 0; r < 4; ++r)
        K[(size_t)(rbase + rowloc + r) * Hn + cbase - 64 + l16] =
            f2b(acc[c6][r]);
    } else {
      const int b  = rbase >> 11;
      const int t0 = (rbase & 2047) + rowloc;
      const int h  = cbase - 128 + l16;
      ushort4v v;
#pragma unroll
      for (int r = 0; r < 4; ++r) v[r] = f2b(acc[c6][r]);
      *reinterpret_cast<ushort4v*>(&Vt[((size_t)b * Hn + h) * Tn + t0]) = v;
    }
  }
}

// ---------------------------------------------------------------------------
// flash: block = 256 thr = 4 waves, 64 q-rows (4 subtiles of 16).
// XCD-aware mapping: XCD = blockIdx%8 (HW round-robin); batch = xcd|((j&1)<<3)
// puts batches {b, b+8} entirely on XCD b -> Q/K/Vt L2-resident (1.5 MB/XCD).
// Wave w handles kv tiles kt = w, w+4, ... for all 4 q-subtiles.
// ---------------------------------------------------------------------------
__global__ __launch_bounds__(256) void flash_kernel(
    const unsigned short* __restrict__ Q, const unsigned short* __restrict__ K,
    const unsigned short* __restrict__ Vt, float* __restrict__ out) {
  __shared__ alignas(16) unsigned short P[4][16][64];  // per-wave, XOR-swizzled
  __shared__ alignas(16) float Om[4][16][68];          // merge: O partials [q][h]
  __shared__ float Ml[4][16][2];                       // merge: m,l per q-row

  const int tid  = threadIdx.x;
  const int wave = tid >> 6;
  const int lane = tid & 63;
  const int quad = lane >> 4;
  const int l16  = lane & 15;

  const int xcd = blockIdx.x & 7;
  const int jb  = blockIdx.x >> 3;           // 0..63
  const int b   = xcd | ((jb & 1) << 3);     // batches {xcd, xcd+8} on XCD xcd
  const int p   = 31 - (jb >> 1);            // heavy q-blocks first
  const int qbase = p * 64;
  const int n_tiles  = p + 1;                // kv tiles of 64 needed
  const int lastTile = p;
  const size_t bbase  = (size_t)b * Tn * Hn;
  const size_t vtbase = (size_t)b * Hn * Tn;

  // B-operand (Q): B[k=h][n=qrow]: lane reads Q[qbase+qt*16+l16][kk*32+quad*8+j]
  bf16x8 qf[4][2];
#pragma unroll
  for (int qt = 0; qt < 4; ++qt)
#pragma unroll
    for (int i = 0; i < 2; ++i)
      qf[qt][i] = *reinterpret_cast<const bf16x8*>(
          &Q[bbase + (size_t)(qbase + qt * 16 + l16) * Hn + i * 32 + quad * 8]);

  // O^T[qt][h = ht*16 + quad*4 + r][q = l16]
  floatx4 O[4][4];
#pragma unroll
  for (int qt = 0; qt < 4; ++qt)
#pragma unroll
    for (int i = 0; i < 4; ++i) O[qt][i] = (floatx4){0.f, 0.f, 0.f, 0.f};
  float m_r[4], l_r[4];
#pragma unroll
  for (int qt = 0; qt < 4; ++qt) { m_r[qt] = -INFINITY; l_r[qt] = 0.f; }

  const int swz = (l16 & 7) << 3;   // 16B-block XOR swizzle (short units)

  for (int kt = wave; kt < n_tiles; kt += 4) {
    const int kvbase = kt * 64;

    // K fragments once per tile, held across both q-halves (2x reuse);
    // V fragments once per tile (4x reuse). Latency hides under QK^T.
    bf16x8 kf[4][2];
#pragma unroll
    for (int ct = 0; ct < 4; ++ct) {
      const unsigned short* kp =
          &K[bbase + (size_t)(kvbase + ct * 16 + l16) * Hn + quad * 8];
      kf[ct][0] = *reinterpret_cast<const bf16x8*>(kp);
      kf[ct][1] = *reinterpret_cast<const bf16x8*>(kp + 32);
    }
    bf16x8 vf[4][2];
#pragma unroll
    for (int ht = 0; ht < 4; ++ht)
#pragma unroll
      for (int kk = 0; kk < 2; ++kk)
        vf[ht][kk] = *reinterpret_cast<const bf16x8*>(
            &Vt[vtbase + (size_t)(ht * 16 + l16) * Tn + kvbase + kk * 32 + quad * 8]);

#pragma unroll
    for (int half = 0; half < 2; ++half) {
      // S^T = mfma(A=K, B=Q) for q-subtiles {2*half, 2*half+1}
      floatx4 S[2][4];
      __builtin_amdgcn_s_setprio(1);
#pragma unroll
      for (int ct = 0; ct < 4; ++ct) {
#pragma unroll
        for (int q2 = 0; q2 < 2; ++q2) {
          const int qt = half * 2 + q2;
          floatx4 s = (floatx4){0.f, 0.f, 0.f, 0.f};
          s = __builtin_amdgcn_mfma_f32_16x16x32_bf16(kf[ct][0], qf[qt][0], s, 0, 0, 0);
          s = __builtin_amdgcn_mfma_f32_16x16x32_bf16(kf[ct][1], qf[qt][1], s, 0, 0, 0);
          S[q2][ct] = s;
        }
      }
      __builtin_amdgcn_s_setprio(0);

#pragma unroll
      for (int q2 = 0; q2 < 2; ++q2) {
        const int qt = half * 2 + q2;
        const int trow = qbase + qt * 16 + l16;

        // causal mask — only the globally-last tile crosses the diagonal
        if (kt == lastTile) {
#pragma unroll
          for (int ct = 0; ct < 4; ++ct)
#pragma unroll
            for (int r = 0; r < 4; ++r)
              if (kvbase + ct * 16 + quad * 4 + r > trow) S[q2][ct][r] = -1e30f;
        }

        // online softmax: lane owns q-row; local tree + 2 cross-quad
        // shfl_xor. Exact defer-max: rescale only when the max grows.
        float mx0 = fmaxf(fmaxf(S[q2][0][0], S[q2][0][1]), fmaxf(S[q2][0][2], S[q2][0][3]));
        float mx1 = fmaxf(fmaxf(S[q2][1][0], S[q2][1][1]), fmaxf(S[q2][1][2], S[q2][1][3]));
        float mx2 = fmaxf(fmaxf(S[q2][2][0], S[q2][2][1]), fmaxf(S[q2][2][2], S[q2][2][3]));
        float mx3 = fmaxf(fmaxf(S[q2][3][0], S[q2][3][1]), fmaxf(S[q2][3][2], S[q2][3][3]));
        float mx  = fmaxf(fmaxf(mx0, mx1), fmaxf(mx2, mx3));
        mx = fmaxf(mx, __shfl_xor(mx, 16));
        mx = fmaxf(mx, __shfl_xor(mx, 32));
        if (mx > m_r[qt]) {
          float alpha = __builtin_amdgcn_exp2f(m_r[qt] - mx);
          l_r[qt] *= alpha;
#pragma unroll
          for (int ht = 0; ht < 4; ++ht)
#pragma unroll
            for (int r = 0; r < 4; ++r) O[qt][ht][r] *= alpha;
          m_r[qt] = mx;
        }
        float rs = 0.f;
#pragma unroll
        for (int ct = 0; ct < 4; ++ct)
#pragma unroll
          for (int r = 0; r < 4; ++r) {
            float pv = __builtin_amdgcn_exp2f(S[q2][ct][r] - m_r[qt]);
            S[q2][ct][r] = pv;
            rs += pv;
          }
        rs += __shfl_xor(rs, 16);
        rs += __shfl_xor(rs, 32);
        l_r[qt] += rs;

        // pack P -> bf16 pairs, swizzled ds_write_b64, read B-frags b128.
        // Same-wave DS ordering: no barrier.
#pragma unroll
        for (int ct = 0; ct < 4; ++ct) {
          uint2v w;
          w[0] = cvt_pk_bf16(S[q2][ct][0], S[q2][ct][1]);
          w[1] = cvt_pk_bf16(S[q2][ct][2], S[q2][ct][3]);
          *reinterpret_cast<uint2v*>(&P[wave][l16][(ct * 16 + quad * 4) ^ swz]) = w;
        }
        bf16x8 pf0 = *reinterpret_cast<const bf16x8*>(&P[wave][l16][(quad * 8) ^ swz]);
        bf16x8 pf1 = *reinterpret_cast<const bf16x8*>(&P[wave][l16][(32 + quad * 8) ^ swz]);

        __builtin_amdgcn_s_setprio(1);
#pragma unroll
        for (int ht = 0; ht < 4; ++ht) {
          O[qt][ht] = __builtin_amdgcn_mfma_f32_16x16x32_bf16(vf[ht][0], pf0, O[qt][ht], 0, 0, 0);
          O[qt][ht] = __builtin_amdgcn_mfma_f32_16x16x32_bf16(vf[ht][1], pf1, O[qt][ht], 0, 0, 0);
        }
        __builtin_amdgcn_s_setprio(0);
      }
    }
  }

  // ---- per-subtile 4-way merge across waves ----
#pragma unroll
  for (int qt = 0; qt < 4; ++qt) {
#pragma unroll
    for (int ht = 0; ht < 4; ++ht)
#pragma unroll
      for (int r = 0; r < 4; ++r)
        Om[wave][l16][ht * 16 + quad * 4 + r] = O[qt][ht][r];
    if (quad == 0) {
      Ml[wave][l16][0] = m_r[qt];
      Ml[wave][l16][1] = l_r[qt];
    }
    __syncthreads();

    {
      const int row = tid >> 4;           // 0..15
      const int c4  = (tid & 15) * 4;     // 0,4,..,60
      float m0 = Ml[0][row][0], m1 = Ml[1][row][0];
      float m2 = Ml[2][row][0], m3 = Ml[3][row][0];
      float M = fmaxf(fmaxf(m0, m1), fmaxf(m2, m3));
      float e0 = __builtin_amdgcn_exp2f(m0 - M), e1 = __builtin_amdgcn_exp2f(m1 - M);
      float e2 = __builtin_amdgcn_exp2f(m2 - M), e3 = __builtin_amdgcn_exp2f(m3 - M);
      float L = Ml[0][row][1] * e0 + Ml[1][row][1] * e1 +
                Ml[2][row][1] * e2 + Ml[3][row][1] * e3;
      float invL = 1.0f / L;
      floatx4 o0 = *reinterpret_cast<const floatx4*>(&Om[0][row][c4]);
      floatx4 o1 = *reinterpret_cast<const floatx4*>(&Om[1][row][c4]);
      floatx4 o2 = *reinterpret_cast<const floatx4*>(&Om[2][row][c4]);
      floatx4 o3 = *reinterpret_cast<const floatx4*>(&Om[3][row][c4]);
      floatx4 res;
#pragma unroll
      for (int jj = 0; jj < 4; ++jj)
        res[jj] = (o0[jj] * e0 + o1[jj] * e1 + o2[jj] * e2 + o3[jj] * e3) * invL;
      *reinterpret_cast<floatx4*>(
          &out[bbase + (size_t)(qbase + qt * 16 + row) * Hn + c4]) = res;
    }
    __syncthreads();
  }
}

// ---------------------------------------------------------------------------
extern "C" void kernel_launch(void* const* d_in, const int* in_sizes, int n_in,
                              void* d_out, int out_size, void* d_ws, size_t ws_size,
                              hipStream_t stream) {
  const float* x  = (const float*)d_in[0];
  const float* Wq = (const float*)d_in[1];
  const float* Wk = (const float*)d_in[2];
  const float* Wv = (const float*)d_in[3];
  float* out = (float*)d_out;

  char* ws = (char*)d_ws;
  unsigned short* Q  = (unsigned short*)(ws);
  unsigned short* Kb = (unsigned short*)(ws + ((size_t)4 << 20));
  unsigned short* Vt = (unsigned short*)(ws + ((size_t)8 << 20));
  unsigned short* Wp = (unsigned short*)(ws + ((size_t)12 << 20));

  pack_w<<<dim3(768), dim3(256), 0, stream>>>(Wq, Wk, Wv, Wp);
  proj_kernel<<<dim3(BT / 64), dim3(512), 0, stream>>>(x, Wp, Q, Kb, Vt);
  flash_kernel<<<dim3(16 * 32), dim3(256), 0, stream>>>(Q, Kb, Vt, out);
}

// Round 11
// 244.065 us; speedup vs baseline: 1.0944x; 1.0057x over previous
//
#include <hip/hip_runtime.h>

// Single causal attention head: B=16, T=2048, C=1024, H=64.
// pack_w: W fp32 -> bf16 Wp, layout matched to global_load_lds B-staging.
// proj:   x[32768,1024]fp32 x Wp -> Q(pre-scaled by 0.125*log2e),K row-major
//         bf16 + Vt[b][h][t] bf16. 8 waves/512 thr, 64-row tile (R10-best)
//         + T3/T4: TRIPLE-buffered B LDS, counted s_waitcnt vmcnt(7) + RAW
//         s_barrier per phase (no vmcnt(0) drain — the compiler's implicit
//         drain before __syncthreads was the ~700cyc/step stall). Each wave
//         issues exactly 7 vmem/phase (4 x + 3 gload_lds); vmcnt(7) drains
//         phase t while t+1 stays in flight across the barrier. Buffer b is
//         rewritten 3 phases after its last read (2 barriers apart): WAR-safe.
// flash:  64 q-rows/block, 4 waves stride kv-tiles (split-kv), wave computes
//         all 4 q-subtiles per tile. XCD-aware mapping: batches {b, b+8} on
//         XCD b -> per-XCD L2 working set 1.5 MB < 4 MB. K frags held in
//         regs across both q-halves. Swapped QK^T -> lane-local online
//         softmax, exact defer-max, cvt_pk + swizzled P LDS, swapped PV.
//
// MFMA 16x16x32 bf16 layouts (HW-verified):
//   A[m][k]: m = lane&15, k = (lane>>4)*8 + j
//   B[k][n]: n = lane&15, k = (lane>>4)*8 + j
//   C/D:     col(n) = lane&15, row(m) = (lane>>4)*4 + reg

typedef float  floatx4 __attribute__((ext_vector_type(4)));
typedef __bf16 bf16x8  __attribute__((ext_vector_type(8)));
typedef unsigned short ushort4v __attribute__((ext_vector_type(4)));
typedef unsigned int   uint2v   __attribute__((ext_vector_type(2)));
typedef unsigned int   uint4v   __attribute__((ext_vector_type(4)));

constexpr int Bn = 16;
constexpr int Tn = 2048;
constexpr int Cn = 1024;
constexpr int Hn = 64;
constexpr int BT = Bn * Tn;

// H^-0.5 * log2(e): scores come out in log2 units -> v_exp_f32 directly.
constexpr float QSCALE = 0.125f * 1.44269504088896340736f;

__device__ __forceinline__ unsigned short f2b(float f) {
  unsigned int u = __builtin_bit_cast(unsigned int, f);
  u += 0x7fffu + ((u >> 16) & 1u);
  return (unsigned short)(u >> 16);
}

__device__ __forceinline__ unsigned int cvt_pk_bf16(float lo, float hi) {
  unsigned int r;
  asm("v_cvt_pk_bf16_f32 %0, %1, %2" : "=v"(r) : "v"(lo), "v"(hi));
  return r;
}

// ---------------------------------------------------------------------------
// Wp[ct 0..11][kb 0..127][c 0..15][j 0..7] bf16  (global col = ct*16+c, k = kb*8+j)
// ---------------------------------------------------------------------------
__global__ __launch_bounds__(256) void pack_w(const float* __restrict__ Wq,
                                              const float* __restrict__ Wk,
                                              const float* __restrict__ Wv,
                                              unsigned short* __restrict__ Wp) {
  int gid = blockIdx.x * 256 + threadIdx.x;
  int mat = gid >> 16;
  int rem = gid & 65535;
  int k   = rem >> 6;
  int col = rem & 63;
  const float* W = (mat == 0) ? Wq : (mat == 1) ? Wk : Wv;
  float v = W[rem];
  int kb = k >> 3, j = k & 7, ct = (mat << 2) | (col >> 4), c = col & 15;
  size_t idx = ((((size_t)ct * 128) + kb) * 16 + c) * 8 + j;
  Wp[idx] = f2b(v);
}

// ---------------------------------------------------------------------------
// proj: block = 512 thr = 8 waves, tile 64 rows x 192 cols, BK=64, grid 512.
// Wave w: rows wr*16..+15 (wr=w>>1), cols wc*96..+95 (wc=w&1).
// Per phase t: issue {4 x-loads (t+1), 3 gload_lds (t+1) -> Bl[(t+1)%3]},
// s_waitcnt vmcnt(7) (drain t only), raw s_barrier, sched_barrier, compute
// {cvt, ds_read Bl[t%3], 12 MFMA}. 72 KB LDS, 2 blocks/CU (4 waves/SIMD).
// ---------------------------------------------------------------------------
__global__ __launch_bounds__(512, 4) void proj_kernel(
    const float* __restrict__ x, const unsigned short* __restrict__ Wp,
    unsigned short* __restrict__ Q, unsigned short* __restrict__ K,
    unsigned short* __restrict__ Vt) {
  __shared__ alignas(16) unsigned short Bl[3][12 * 1024];

  const int tid  = threadIdx.x;
  const int wave = tid >> 6;     // 0..7
  const int lane = tid & 63;
  const int quad = lane >> 4;
  const int l16  = lane & 15;
  const int wr   = wave >> 1;    // 0..3 row-sixteenth
  const int wc   = wave & 1;     // 0..1 col-half
  const int rbase = blockIdx.x * 64;

  floatx4 acc[6];
#pragma unroll
  for (int b = 0; b < 6; ++b) acc[b] = (floatx4){0.f, 0.f, 0.f, 0.f};

  // per-lane A pointer: row = rbase + wr*16 + l16, col base = quad*8
  const float* xp = x + (size_t)(rbase + wr * 16 + l16) * Cn + quad * 8;

  // 24 (ct,h) staging slots spread over 8 waves x 3: p = wave*3+i,
  // ct = p>>1, h = p&1  (bijection onto 12 cts x 2 halves).
  auto stageB = [&](int t, int buf) {
    const int kb0 = t << 3;
#pragma unroll
    for (int i = 0; i < 3; ++i) {
      const int p  = wave * 3 + i;
      const int ct = p >> 1;
      const int h  = p & 1;
      const unsigned short* g =
          Wp + ((size_t)(ct * 128 + kb0 + h * 4 + quad) * 16 + l16) * 8;
      __builtin_amdgcn_global_load_lds(
          (const __attribute__((address_space(1))) void*)g,
          (__attribute__((address_space(3))) void*)&Bl[buf][ct * 1024 + h * 512],
          16, 0, 0);
    }
  };

  auto loadX = [&](int t, floatx4 (&fa)[2][2]) {
    const float* bp = xp + t * 64;
    fa[0][0] = *reinterpret_cast<const floatx4*>(bp);
    fa[0][1] = *reinterpret_cast<const floatx4*>(bp + 4);
    fa[1][0] = *reinterpret_cast<const floatx4*>(bp + 32);
    fa[1][1] = *reinterpret_cast<const floatx4*>(bp + 36);
  };

  auto compute = [&](const floatx4 (&fa)[2][2], int buf) {
    bf16x8 af[2];
#pragma unroll
    for (int kk = 0; kk < 2; ++kk) {
      uint4v u;
      u[0] = cvt_pk_bf16(fa[kk][0][0], fa[kk][0][1]);
      u[1] = cvt_pk_bf16(fa[kk][0][2], fa[kk][0][3]);
      u[2] = cvt_pk_bf16(fa[kk][1][0], fa[kk][1][1]);
      u[3] = cvt_pk_bf16(fa[kk][1][2], fa[kk][1][3]);
      af[kk] = __builtin_bit_cast(bf16x8, u);
    }
    __builtin_amdgcn_s_setprio(1);
#pragma unroll
    for (int kk = 0; kk < 2; ++kk) {
#pragma unroll
      for (int c6 = 0; c6 < 6; ++c6) {
        const int ct = wc * 6 + c6;
        bf16x8 bfr = *reinterpret_cast<const bf16x8*>(
            &Bl[buf][ct * 1024 + (kk * 4 + quad) * 128 + l16 * 8]);
        acc[c6] = __builtin_amdgcn_mfma_f32_16x16x32_bf16(af[kk], bfr, acc[c6], 0, 0, 0);
      }
    }
    __builtin_amdgcn_s_setprio(0);
  };

  floatx4 fa0[2][2], fa1[2][2];

  // prologue: phase-0 loads in flight (7 vmem ops/wave)
  loadX(0, fa0);
  stageB(0, 0);

  for (int tt = 0; tt < 8; ++tt) {
    const int t = tt * 2;
    // phase A: cur = t (buf t%3); issue t+1 -> buf (t+1)%3
    loadX(t + 1, fa1);
    stageB(t + 1, (t + 1) % 3);
    asm volatile("s_waitcnt vmcnt(7)" ::: "memory");
    __builtin_amdgcn_s_barrier();
    __builtin_amdgcn_sched_barrier(0);
    compute(fa0, t % 3);
    // phase B: cur = t+1; issue t+2 -> buf (t+2)%3
    if (t + 2 < 16) {
      loadX(t + 2, fa0);
      stageB(t + 2, (t + 2) % 3);
      asm volatile("s_waitcnt vmcnt(7)" ::: "memory");
    } else {
      asm volatile("s_waitcnt vmcnt(0)" ::: "memory");
    }
    __builtin_amdgcn_s_barrier();
    __builtin_amdgcn_sched_barrier(0);
    compute(fa1, (t + 1) % 3);
  }

#pragma unroll
  for (int c6 = 0; c6 < 6; ++c6) {
    const int cbase  = wc * 96 + c6 * 16;
    const int rowloc = wr * 16 + quad * 4;
    if (cbase < 64) {
#pragma unroll
      for (int r = 0; r < 4; ++r)
        Q[(size_t)(rbase + rowloc + r) * Hn + cbase + l16] =
            f2b(acc[c6][r] * QSCALE);
    } else if (cbase < 128) {
#pragma unroll
      for (int r = 0; r < 4; ++r)
        K[(size_t)(rbase + rowloc + r) * Hn + cbase - 64 + l16] =
            f2b(acc[c6][r]);
    } else {
      const int b  = rbase >> 11;
      const int t0 = (rbase & 2047) + rowloc;
      const int h  = cbase - 128 + l16;
      ushort4v v;
#pragma unroll
      for (int r = 0; r < 4; ++r) v[r] = f2b(acc[c6][r]);
      *reinterpret_cast<ushort4v*>(&Vt[((size_t)b * Hn + h) * Tn + t0]) = v;
    }
  }
}

// ---------------------------------------------------------------------------
// flash: block = 256 thr = 4 waves, 64 q-rows (4 subtiles of 16).
// XCD-aware mapping: XCD = blockIdx%8 (HW round-robin); batch = xcd|((j&1)<<3)
// puts batches {b, b+8} entirely on XCD b -> Q/K/Vt L2-resident (1.5 MB/XCD).
// Wave w handles kv tiles kt = w, w+4, ... for all 4 q-subtiles.
// ---------------------------------------------------------------------------
__global__ __launch_bounds__(256) void flash_kernel(
    const unsigned short* __restrict__ Q, const unsigned short* __restrict__ K,
    const unsigned short* __restrict__ Vt, float* __restrict__ out) {
  __shared__ alignas(16) unsigned short P[4][16][64];  // per-wave, XOR-swizzled
  __shared__ alignas(16) float Om[4][16][68];          // merge: O partials [q][h]
  __shared__ float Ml[4][16][2];                       // merge: m,l per q-row

  const int tid  = threadIdx.x;
  const int wave = tid >> 6;
  const int lane = tid & 63;
  const int quad = lane >> 4;
  const int l16  = lane & 15;

  const int xcd = blockIdx.x & 7;
  const int jb  = blockIdx.x >> 3;           // 0..63
  const int b   = xcd | ((jb & 1) << 3);     // batches {xcd, xcd+8} on XCD xcd
  const int p   = 31 - (jb >> 1);            // heavy q-blocks first
  const int qbase = p * 64;
  const int n_tiles  = p + 1;                // kv tiles of 64 needed
  const int lastTile = p;
  const size_t bbase  = (size_t)b * Tn * Hn;
  const size_t vtbase = (size_t)b * Hn * Tn;

  // B-operand (Q): B[k=h][n=qrow]: lane reads Q[qbase+qt*16+l16][kk*32+quad*8+j]
  bf16x8 qf[4][2];
#pragma unroll
  for (int qt = 0; qt < 4; ++qt)
#pragma unroll
    for (int i = 0; i < 2; ++i)
      qf[qt][i] = *reinterpret_cast<const bf16x8*>(
          &Q[bbase + (size_t)(qbase + qt * 16 + l16) * Hn + i * 32 + quad * 8]);

  // O^T[qt][h = ht*16 + quad*4 + r][q = l16]
  floatx4 O[4][4];
#pragma unroll
  for (int qt = 0; qt < 4; ++qt)
#pragma unroll
    for (int i = 0; i < 4; ++i) O[qt][i] = (floatx4){0.f, 0.f, 0.f, 0.f};
  float m_r[4], l_r[4];
#pragma unroll
  for (int qt = 0; qt < 4; ++qt) { m_r[qt] = -INFINITY; l_r[qt] = 0.f; }

  const int swz = (l16 & 7) << 3;   // 16B-block XOR swizzle (short units)

  for (int kt = wave; kt < n_tiles; kt += 4) {
    const int kvbase = kt * 64;

    // K fragments once per tile, held across both q-halves (2x reuse);
    // V fragments once per tile (4x reuse). Latency hides under QK^T.
    bf16x8 kf[4][2];
#pragma unroll
    for (int ct = 0; ct < 4; ++ct) {
      const unsigned short* kp =
          &K[bbase + (size_t)(kvbase + ct * 16 + l16) * Hn + quad * 8];
      kf[ct][0] = *reinterpret_cast<const bf16x8*>(kp);
      kf[ct][1] = *reinterpret_cast<const bf16x8*>(kp + 32);
    }
    bf16x8 vf[4][2];
#pragma unroll
    for (int ht = 0; ht < 4; ++ht)
#pragma unroll
      for (int kk = 0; kk < 2; ++kk)
        vf[ht][kk] = *reinterpret_cast<const bf16x8*>(
            &Vt[vtbase + (size_t)(ht * 16 + l16) * Tn + kvbase + kk * 32 + quad * 8]);

#pragma unroll
    for (int half = 0; half < 2; ++half) {
      // S^T = mfma(A=K, B=Q) for q-subtiles {2*half, 2*half+1}
      floatx4 S[2][4];
      __builtin_amdgcn_s_setprio(1);
#pragma unroll
      for (int ct = 0; ct < 4; ++ct) {
#pragma unroll
        for (int q2 = 0; q2 < 2; ++q2) {
          const int qt = half * 2 + q2;
          floatx4 s = (floatx4){0.f, 0.f, 0.f, 0.f};
          s = __builtin_amdgcn_mfma_f32_16x16x32_bf16(kf[ct][0], qf[qt][0], s, 0, 0, 0);
          s = __builtin_amdgcn_mfma_f32_16x16x32_bf16(kf[ct][1], qf[qt][1], s, 0, 0, 0);
          S[q2][ct] = s;
        }
      }
      __builtin_amdgcn_s_setprio(0);

#pragma unroll
      for (int q2 = 0; q2 < 2; ++q2) {
        const int qt = half * 2 + q2;
        const int trow = qbase + qt * 16 + l16;

        // causal mask — only the globally-last tile crosses the diagonal
        if (kt == lastTile) {
#pragma unroll
          for (int ct = 0; ct < 4; ++ct)
#pragma unroll
            for (int r = 0; r < 4; ++r)
              if (kvbase + ct * 16 + quad * 4 + r > trow) S[q2][ct][r] = -1e30f;
        }

        // online softmax: lane owns q-row; local tree + 2 cross-quad
        // shfl_xor. Exact defer-max: rescale only when the max grows.
        float mx0 = fmaxf(fmaxf(S[q2][0][0], S[q2][0][1]), fmaxf(S[q2][0][2], S[q2][0][3]));
        float mx1 = fmaxf(fmaxf(S[q2][1][0], S[q2][1][1]), fmaxf(S[q2][1][2], S[q2][1][3]));
        float mx2 = fmaxf(fmaxf(S[q2][2][0], S[q2][2][1]), fmaxf(S[q2][2][2], S[q2][2][3]));
        float mx3 = fmaxf(fmaxf(S[q2][3][0], S[q2][3][1]), fmaxf(S[q2][3][2], S[q2][3][3]));
        float mx  = fmaxf(fmaxf(mx0, mx1), fmaxf(mx2, mx3));
        mx = fmaxf(mx, __shfl_xor(mx, 16));
        mx = fmaxf(mx, __shfl_xor(mx, 32));
        if (mx > m_r[qt]) {
          float alpha = __builtin_amdgcn_exp2f(m_r[qt] - mx);
          l_r[qt] *= alpha;
#pragma unroll
          for (int ht = 0; ht < 4; ++ht)
#pragma unroll
            for (int r = 0; r < 4; ++r) O[qt][ht][r] *= alpha;
          m_r[qt] = mx;
        }
        float rs = 0.f;
#pragma unroll
        for (int ct = 0; ct < 4; ++ct)
#pragma unroll
          for (int r = 0; r < 4; ++r) {
            float pv = __builtin_amdgcn_exp2f(S[q2][ct][r] - m_r[qt]);
            S[q2][ct][r] = pv;
            rs += pv;
          }
        rs += __shfl_xor(rs, 16);
        rs += __shfl_xor(rs, 32);
        l_r[qt] += rs;

        // pack P -> bf16 pairs, swizzled ds_write_b64, read B-frags b128.
        // Same-wave DS ordering: no barrier.
#pragma unroll
        for (int ct = 0; ct < 4; ++ct) {
          uint2v w;
          w[0] = cvt_pk_bf16(S[q2][ct][0], S[q2][ct][1]);
          w[1] = cvt_pk_bf16(S[q2][ct][2], S[q2][ct][3]);
          *reinterpret_cast<uint2v*>(&P[wave][l16][(ct * 16 + quad * 4) ^ swz]) = w;
        }
        bf16x8 pf0 = *reinterpret_cast<const bf16x8*>(&P[wave][l16][(quad * 8) ^ swz]);
        bf16x8 pf1 = *reinterpret_cast<const bf16x8*>(&P[wave][l16][(32 + quad * 8) ^ swz]);

        __builtin_amdgcn_s_setprio(1);
#pragma unroll
        for (int ht = 0; ht < 4; ++ht) {
          O[qt][ht] = __builtin_amdgcn_mfma_f32_16x16x32_bf16(vf[ht][0], pf0, O[qt][ht], 0, 0, 0);
          O[qt][ht] = __builtin_amdgcn_mfma_f32_16x16x32_bf16(vf[ht][1], pf1, O[qt][ht], 0, 0, 0);
        }
        __builtin_amdgcn_s_setprio(0);
      }
    }
  }

  // ---- per-subtile 4-way merge across waves ----
#pragma unroll
  for (int qt = 0; qt < 4; ++qt) {
#pragma unroll
    for (int ht = 0; ht < 4; ++ht)
#pragma unroll
      for (int r = 0; r < 4; ++r)
        Om[wave][l16][ht * 16 + quad * 4 + r] = O[qt][ht][r];
    if (quad == 0) {
      Ml[wave][l16][0] = m_r[qt];
      Ml[wave][l16][1] = l_r[qt];
    }
    __syncthreads();

    {
      const int row = tid >> 4;           // 0..15
      const int c4  = (tid & 15) * 4;     // 0,4,..,60
      float m0 = Ml[0][row][0], m1 = Ml[1][row][0];
      float m2 = Ml[2][row][0], m3 = Ml[3][row][0];
      float M = fmaxf(fmaxf(m0, m1), fmaxf(m2, m3));
      float e0 = __builtin_amdgcn_exp2f(m0 - M), e1 = __builtin_amdgcn_exp2f(m1 - M);
      float e2 = __builtin_amdgcn_exp2f(m2 - M), e3 = __builtin_amdgcn_exp2f(m3 - M);
      float L = Ml[0][row][1] * e0 + Ml[1][row][1] * e1 +
                Ml[2][row][1] * e2 + Ml[3][row][1] * e3;
      float invL = 1.0f / L;
      floatx4 o0 = *reinterpret_cast<const floatx4*>(&Om[0][row][c4]);
      floatx4 o1 = *reinterpret_cast<const floatx4*>(&Om[1][row][c4]);
      floatx4 o2 = *reinterpret_cast<const floatx4*>(&Om[2][row][c4]);
      floatx4 o3 = *reinterpret_cast<const floatx4*>(&Om[3][row][c4]);
      floatx4 res;
#pragma unroll
      for (int jj = 0; jj < 4; ++jj)
        res[jj] = (o0[jj] * e0 + o1[jj] * e1 + o2[jj] * e2 + o3[jj] * e3) * invL;
      *reinterpret_cast<floatx4*>(
          &out[bbase + (size_t)(qbase + qt * 16 + row) * Hn + c4]) = res;
    }
    __syncthreads();
  }
}

// ---------------------------------------------------------------------------
extern "C" void kernel_launch(void* const* d_in, const int* in_sizes, int n_in,
                              void* d_out, int out_size, void* d_ws, size_t ws_size,
                              hipStream_t stream) {
  const float* x  = (const float*)d_in[0];
  const float* Wq = (const float*)d_in[1];
  const float* Wk = (const float*)d_in[2];
  const float* Wv = (const float*)d_in[3];
  float* out = (float*)d_out;

  char* ws = (char*)d_ws;
  unsigned short* Q  = (unsigned short*)(ws);
  unsigned short* Kb = (unsigned short*)(ws + ((size_t)4 << 20));
  unsigned short* Vt = (unsigned short*)(ws + ((size_t)8 << 20));
  unsigned short* Wp = (unsigned short*)(ws + ((size_t)12 << 20));

  pack_w<<<dim3(768), dim3(256), 0, stream>>>(Wq, Wk, Wv, Wp);
  proj_kernel<<<dim3(BT / 64), dim3(512), 0, stream>>>(x, Wp, Q, Kb, Vt);
  flash_kernel<<<dim3(16 * 32), dim3(256), 0, stream>>>(Q, Kb, Vt, out);
}